// Round 11
// baseline (201.287 us; speedup 1.0000x reference)
//
#include <hip/hip_runtime.h>
#include <hip/hip_fp16.h>
#include <math.h>

#define HID 32
#define NFEAT 100
#define CHUNK 8192   // edges per sort chunk
#define NCMAX 256    // max chunks (E/CHUNK = 196)
#define NBMAX 1600   // max buckets (N/64 = 1563)
#define LOCB 64      // target nodes per bucket (6-bit local id)
#define CAP 1536     // LDS edge capacity per bucket (mean 1024, sd 32 -> +16 sigma)

typedef _Float16 half2_v __attribute__((ext_vector_type(2)));
__device__ __forceinline__ float fdot2u(unsigned int a, unsigned int b, float c) {
    return __builtin_amdgcn_fdot2(*(half2_v*)&a, *(half2_v*)&b, c, false);
}
__device__ __forceinline__ float2 h2f(unsigned int u) {
    return __half22float2(*(__half2*)&u);
}
__device__ __forceinline__ float4 h4_to_f4(uint2 u) {
    float2 a = h2f(u.x), b = h2f(u.y);
    return make_float4(a.x, a.y, b.x, b.y);
}
__device__ __forceinline__ unsigned int packh2(float a, float b) {
    __half2 t = __floats2half2_rn(a, b);
    return *(unsigned int*)&t;
}

// ================= Phase 1: k1 blocks and sort blocks interleaved (2:1) =================
// u%3==2 -> sort chunk u/3; else k1 unit (u/3)*2 + u%3 (256 nodes each, thread-per-node).
__global__ __launch_bounds__(256) void k_phase1(
    const float* __restrict__ X, const float* __restrict__ w1,
    const float* __restrict__ b1, const int* __restrict__ ei,
    __half* __restrict__ xh, float* __restrict__ invn,
    int* __restrict__ binned, unsigned short* __restrict__ offU,
    int N, int E, int NB, int NC, int nblk1)
{
    __shared__ __align__(16) char smem[12608];
    const int tid = threadIdx.x;
    const int u = blockIdx.x;
    const int q = u / 3, r = u - q * 3;

    if (r != 2) {
        // ------- k1: thread-per-node. x row in half2 regs; w half2 in LDS (uniform b128) ----
        const int blk = q * 2 + r;
        if (blk >= nblk1) return;
        __half2* wH = (__half2*)smem;                 // [32][52] half2 = 6656 B
        float*   bl = (float*)(smem + 6656);          // 32 floats
        const float4* w14 = (const float4*)w1;        // 800 float4 = w1[32][100]
        for (int i = tid; i < 800; i += 256) {
            float4 v = w14[i];
            int idx = i * 4, h = idx / NFEAT, k = idx % NFEAT;   // k % 4 == 0
            wH[h * 52 + k / 2]     = __floats2half2_rn(v.x, v.y);
            wH[h * 52 + k / 2 + 1] = __floats2half2_rn(v.z, v.w);
        }
        if (tid < 64) {   // zero-pad halfs 100..103 of each row
            __half2 z; z.x = __float2half(0.f); z.y = __float2half(0.f);
            wH[(tid >> 1) * 52 + 50 + (tid & 1)] = z;
        }
        if (tid < 32) bl[tid] = b1[tid];
        __syncthreads();

        const int node = blk * 256 + tid;
        const int nc = node < N ? node : N - 1;
        const float4* Xr = (const float4*)(X + (size_t)nc * NFEAT);
        unsigned int xu[52];
        #pragma unroll
        for (int qq = 0; qq < 25; ++qq) {
            float4 v = Xr[qq];
            xu[2 * qq]     = packh2(v.x, v.y);
            xu[2 * qq + 1] = packh2(v.z, v.w);
        }
        xu[50] = 0; xu[51] = 0;

        float ssum = 0.f;
        unsigned int op[16];
        float vprev = 0.f;
        #pragma unroll
        for (int h = 0; h < HID; ++h) {
            const uint4* wrow = (const uint4*)(wH + h * 52);
            float acc = 0.f;
            #pragma unroll
            for (int t = 0; t < 13; ++t) {
                uint4 wv = wrow[t];
                acc = fdot2u(xu[4 * t + 0], wv.x, acc);
                acc = fdot2u(xu[4 * t + 1], wv.y, acc);
                acc = fdot2u(xu[4 * t + 2], wv.z, acc);
                acc = fdot2u(xu[4 * t + 3], wv.w, acc);
            }
            float v = fmaxf(acc + bl[h], 0.f);
            ssum = fmaf(v, v, ssum);
            if (h & 1) op[h >> 1] = packh2(vprev, v); else vprev = v;
        }
        const float inv = 1.f / fmaxf(sqrtf(ssum), 1e-12f);
        if (node < N) {
            uint4* dst = (uint4*)(xh + (size_t)node * HID);
            dst[0] = make_uint4(op[0], op[1], op[2], op[3]);
            dst[1] = make_uint4(op[4], op[5], op[6], op[7]);
            dst[2] = make_uint4(op[8], op[9], op[10], op[11]);
            dst[3] = make_uint4(op[12], op[13], op[14], op[15]);
            invn[node] = inv;
        }
    } else {
        // ------- kc_sort: chunk-local counting sort by bucket = tgt>>6 ---------------------
        const int c = q;
        if (c >= NC) return;
        int* hist = (int*)smem;          // NBMAX ints (12.5 KB with off)
        int* off  = hist + NBMAX / 2 * 0 + 1576;   // second region; 1576 >= NB+pad
        const int start = c * CHUNK;
        const int end = min(start + CHUNK, E);
        for (int b = tid; b < NB; b += 256) hist[b] = 0;
        __syncthreads();
        for (int e = start + tid; e < end; e += 256)
            atomicAdd(&hist[ei[E + e] >> 6], 1);
        __syncthreads();
        if (tid < 64) {   // wave 0: exclusive scan, 64 buckets/round with carry
            int carry = 0;
            for (int rr = 0; rr * 64 < NB; ++rr) {
                int b = rr * 64 + tid;
                int v = (b < NB) ? hist[b] : 0;
                int x = v;
                #pragma unroll
                for (int dd = 1; dd < 64; dd <<= 1) {
                    int y = __shfl_up(x, dd, 64);
                    if (tid >= dd) x += y;
                }
                if (b < NB) off[b] = carry + x - v;
                carry += __shfl(x, 63, 64);
            }
        }
        __syncthreads();
        const size_t urow = (size_t)c * (NB + 1);
        for (int b = tid; b < NB; b += 256) {
            offU[urow + b] = (unsigned short)off[b];   // coalesced u16 writes
            hist[b] = off[b];                           // reuse as local cursor
        }
        if (tid == 0) offU[urow + NB] = (unsigned short)(end - start);
        __syncthreads();
        for (int e = start + tid; e < end; e += 256) {
            int t = ei[E + e];
            int b = t >> 6;
            int pos = atomicAdd(&hist[b], 1);
            binned[start + pos] = ei[e] | ((t & 63) << 17);  // src<2^17, local 6 bits
        }
    }
}

// ================= Fused: 1 global pass -> LDS reorder -> pipelined gather =================
__global__ __launch_bounds__(256) void k_fused(
    const int* __restrict__ binned, const unsigned short* __restrict__ offU,
    const __half* __restrict__ xh, const float* __restrict__ invn,
    const float* __restrict__ pbeta,
    const float* __restrict__ w2, const float* __restrict__ b2,
    float* __restrict__ out, int N, int NB, int NC)
{
    __shared__ unsigned short b0s[NCMAX], b1s[NCMAX];
    __shared__ int cnt[LOCB], cur[LOCB];
    __shared__ int led[CAP], led2[CAP];
    __shared__ int bcur_s;
    const int tid  = threadIdx.x;
    const int lane = tid & 63;
    const int wv   = tid >> 6;
    const int g    = lane & 7;   // feature slice: halfs g*4 .. g*4+3
    const int sub  = lane >> 3;  // edge slot 0..7 (slot-uniform across its 8 lanes)
    const int b    = blockIdx.x;
    const int R    = NB + 1;
    const float beta = *pbeta;
    const float w0a = w2[g*4], w0b = w2[g*4+1], w0c = w2[g*4+2], w0d = w2[g*4+3];
    const float w1a = w2[HID+g*4], w1b = w2[HID+g*4+1], w1c = w2[HID+g*4+2], w1d = w2[HID+g*4+3];
    const float bb0 = b2[0], bb1 = b2[1];

    for (int c = tid; c < NC; c += 256) {
        const size_t base = (size_t)c * R + b;
        b0s[c] = offU[base];
        b1s[c] = offU[base + 1];
    }
    if (tid < LOCB) cnt[tid] = 0;
    if (tid == 0) bcur_s = 0;
    __syncthreads();

    // single global pass: append words into led[] unordered + per-node counts
    {
        int total = 0;
        for (int c = tid; c < NC; c += 256) total += (int)b1s[c] - (int)b0s[c];
        int pos = total ? atomicAdd(&bcur_s, total) : 0;
        for (int c = tid; c < NC; c += 256) {
            const int gbase = c * CHUNK;
            const int j1 = b1s[c];
            for (int j = b0s[c]; j < j1; ++j) {
                const int w = binned[gbase + j];
                atomicAdd(&cnt[w >> 17], 1);
                if (pos < CAP) led[pos] = w;
                ++pos;
            }
        }
    }
    __syncthreads();
    const int sz = bcur_s;
    if (tid < 64) {   // exclusive scan of 64 counts
        int v = cnt[tid], x = v;
        #pragma unroll
        for (int dd = 1; dd < 64; dd <<= 1) {
            int y = __shfl_up(x, dd, 64);
            if (tid >= dd) x += y;
        }
        cur[tid] = x - v;
    }
    __syncthreads();
    const bool fits = (sz <= CAP);
    if (fits) {   // LDS->LDS reorder: group src ids by local node
        for (int i = tid; i < sz; i += 256) {
            const int w = led[i];
            const int pos = atomicAdd(&cur[w >> 17], 1);
            led2[pos] = w & 0x1FFFF;
        }
    }
    __syncthreads();

    for (int local = wv; local < LOCB; local += 4) {
        const int node = b * LOCB + local;
        if (node >= N) break;   // monotone -> uniform break per wave

        const float ivt = invn[node];
        const uint2 ut = *(const uint2*)(xh + (size_t)node * HID + g * 4);
        const float4 xt = h4_to_f4(ut);
        float sd = xt.x*xt.x + xt.y*xt.y + xt.z*xt.z + xt.w*xt.w;
        sd += __shfl_xor(sd, 1, 64); sd += __shfl_xor(sd, 2, 64); sd += __shfl_xor(sd, 4, 64);

        float a0 = 0.f, a1 = 0.f, a2 = 0.f, a3 = 0.f, dsum = 0.f;
        const int deg = cnt[local];

        if (fits) {
            const int st = cur[local] - deg;   // cur ended at start+deg
            // software-pipelined: prefetch slot e0+8 while computing slot e0
            bool ok = sub < deg;
            int sc = led2[ok ? st + sub : 0];
            sc = ok ? sc : 0;
            uint2 uc = *(const uint2*)(xh + (size_t)sc * HID + g * 4);
            float ivc = invn[sc];
            for (int e0 = 0; e0 < deg; e0 += 8) {
                const bool okn = (e0 + 8 + sub) < deg;
                int sn = led2[okn ? st + e0 + 8 + sub : 0];
                sn = okn ? sn : 0;
                const uint2 un = *(const uint2*)(xh + (size_t)sn * HID + g * 4);
                const float ivnx = invn[sn];

                const float4 xs = h4_to_f4(uc);
                float p = xt.x*xs.x + xt.y*xs.y + xt.z*xs.z + xt.w*xs.w;
                p += __shfl_xor(p, 1, 64); p += __shfl_xor(p, 2, 64); p += __shfl_xor(p, 4, 64);
                const float wgt = ok ? __expf(beta * p * ivt * ivc) : 0.f;  // cos in [-1,1]
                a0 += wgt*xs.x; a1 += wgt*xs.y; a2 += wgt*xs.z; a3 += wgt*xs.w;
                dsum += wgt;

                uc = un; ivc = ivnx; ok = okn;
            }
        } else {
            // fallback (bucket > CAP, practically never): filter all sub-runs from global
            for (int c = 0; c < NC; ++c) {
                const int gbase = c * CHUNK;
                const int j1 = b1s[c];
                for (int j = (int)b0s[c] + sub; j < j1; j += 8) {
                    const int wrd = binned[gbase + j];
                    const bool ok2 = ((wrd >> 17) == local);
                    const int s_ = ok2 ? (wrd & 0x1FFFF) : 0;
                    const uint2 us = *(const uint2*)(xh + (size_t)s_ * HID + g * 4);
                    const float4 xs = h4_to_f4(us);
                    float p = xt.x*xs.x + xt.y*xs.y + xt.z*xs.z + xt.w*xs.w;
                    p += __shfl_xor(p, 1, 64); p += __shfl_xor(p, 2, 64); p += __shfl_xor(p, 4, 64);
                    const float ivs = invn[s_];
                    const float wgt = ok2 ? __expf(beta * p * ivt * ivs) : 0.f;
                    a0 += wgt*xs.x; a1 += wgt*xs.y; a2 += wgt*xs.z; a3 += wgt*xs.w;
                    dsum += wgt;
                }
            }
        }
        #pragma unroll
        for (int m = 8; m <= 32; m <<= 1) {
            a0 += __shfl_xor(a0, m, 64); a1 += __shfl_xor(a1, m, 64);
            a2 += __shfl_xor(a2, m, 64); a3 += __shfl_xor(a3, m, 64);
            dsum += __shfl_xor(dsum, m, 64);
        }
        // self-loop
        const float wself = __expf(beta * sd * ivt * ivt);
        a0 += wself*xt.x; a1 += wself*xt.y; a2 += wself*xt.z; a3 += wself*xt.w;
        dsum += wself;

        const float invd = 1.f / dsum;
        const float o0 = a0*invd, o1 = a1*invd, o2 = a2*invd, o3 = a3*invd;
        float l0 = o0*w0a + o1*w0b + o2*w0c + o3*w0d;
        float l1 = o0*w1a + o1*w1b + o2*w1c + o3*w1d;
        l0 += __shfl_xor(l0, 1, 64); l0 += __shfl_xor(l0, 2, 64); l0 += __shfl_xor(l0, 4, 64);
        l1 += __shfl_xor(l1, 1, 64); l1 += __shfl_xor(l1, 2, 64); l1 += __shfl_xor(l1, 4, 64);
        if (lane == 0) {
            l0 += bb0; l1 += bb1;
            float m = fmaxf(l0, l1);
            float lse = m + __logf(__expf(l0 - m) + __expf(l1 - m));
            out[2 * (size_t)node]     = l0 - lse;
            out[2 * (size_t)node + 1] = l1 - lse;
        }
    }
}

extern "C" void kernel_launch(void* const* d_in, const int* in_sizes, int n_in,
                              void* d_out, int out_size, void* d_ws, size_t ws_size,
                              hipStream_t stream) {
    const float* X    = (const float*)d_in[0];
    const float* w1   = (const float*)d_in[1];
    const float* b1   = (const float*)d_in[2];
    const float* beta = (const float*)d_in[3];
    const float* w2   = (const float*)d_in[4];
    const float* b2   = (const float*)d_in[5];
    const int*   ei   = (const int*)d_in[6];

    const int N = in_sizes[0] / NFEAT;        // 100000
    const int E = in_sizes[6] / 2;            // 1600000
    const int NB = (N + LOCB - 1) / LOCB;     // 1563 buckets of 64 nodes
    const int NC = (E + CHUNK - 1) / CHUNK;   // 196 chunks
    const int R  = NB + 1;                    // offset-table row length
    const int nblk1 = (N + 255) / 256;        // 391 k1 units (256 nodes each)

    char* wsb = (char*)d_ws;
    __half* xhp   = (__half*)wsb;                 wsb += (size_t)N * HID * 2;   // 6.4 MB
    float*  invn  = (float*)wsb;                  wsb += (size_t)N * 4;
    int*    binned = (int*)wsb;                   wsb += (size_t)E * 4;         // 6.4 MB
    unsigned short* offU = (unsigned short*)wsb;  wsb += (size_t)NC * R * 2;    // 0.6 MB
    float* out = (float*)d_out;

    const int k1grp = (nblk1 + 1) / 2;            // 196
    const int gridA = (k1grp > NC ? k1grp : NC) * 3;   // 588 interleaved blocks

    k_phase1<<<gridA, 256, 0, stream>>>(X, w1, b1, ei, xhp, invn,
                                        binned, offU, N, E, NB, NC, nblk1);
    k_fused<<<NB, 256, 0, stream>>>(binned, offU, xhp, invn, beta, w2, b2, out, N, NB, NC);
}

// Round 12
// 191.602 us; speedup vs baseline: 1.0505x; 1.0505x over previous
//
#include <hip/hip_runtime.h>
#include <hip/hip_fp16.h>
#include <math.h>

#define HID 32
#define NFEAT 100
#define CHUNK 4096   // edges per sort chunk
#define NCMAX 512    // max chunks (E/CHUNK = 391)
#define NBMAX 1600   // max buckets (N/64 = 1563)
#define LOCB 64      // target nodes per bucket (6-bit local id)
#define CAP 1536     // LDS edge capacity per bucket (mean 1024, sd 32 -> +16 sigma)

typedef _Float16 half2_v __attribute__((ext_vector_type(2)));
__device__ __forceinline__ float2 h2f(unsigned int u) {
    return __half22float2(*(__half2*)&u);
}
__device__ __forceinline__ float4 h4_to_f4(uint2 u) {
    float2 a = h2f(u.x), b = h2f(u.y);
    return make_float4(a.x, a.y, b.x, b.y);
}

// ================= Phase 1 (R10 form): k1 blocks and sort blocks interleaved 4:1 ===========
__global__ __launch_bounds__(256) void k_phase1(
    const float* __restrict__ X, const float* __restrict__ w1,
    const float* __restrict__ b1, const int* __restrict__ ei,
    __half* __restrict__ xh, float* __restrict__ invn,
    int* __restrict__ binned, unsigned short* __restrict__ offU,
    int N, int E, int NB, int NC, int nblk1)
{
    __shared__ __align__(16) char smem[26048];
    const int tid = threadIdx.x;
    const int u = blockIdx.x;
    const int q = u / 5, r = u - q * 5;

    if (r != 4) {
        // ---------------- k1: xh = fp16(relu(X@w1^T+b1)); invn = 1/max(||x||,eps) ----------
        const int blk = q * 4 + r;
        if (blk >= nblk1) return;
        float*   wT  = (float*)smem;                    // [100][33] fp32, 13200 B
        __half2* xsH = (__half2*)(smem + 13216);        // [64][50] half2, 12800 B
        const float4* w14 = (const float4*)w1;          // 800 float4
        for (int i = tid; i < 800; i += 256) {
            float4 v = w14[i];
            int idx = i * 4, h = idx / NFEAT, k = idx % NFEAT;
            wT[k * 33 + h] = v.x; wT[(k + 1) * 33 + h] = v.y;
            wT[(k + 2) * 33 + h] = v.z; wT[(k + 3) * 33 + h] = v.w;
        }
        const int n0 = blk * 64;
        const float4* X4 = (const float4*)X;            // row = 25 float4
        for (int i = tid; i < 1600; i += 256) {
            int rr = i / 25, qq = i % 25;
            int node = n0 + rr;
            float4 v = (node < N) ? X4[(size_t)node * 25 + qq] : make_float4(0.f, 0.f, 0.f, 0.f);
            xsH[rr * 50 + 2 * qq]     = __floats2half2_rn(v.x, v.y);
            xsH[rr * 50 + 2 * qq + 1] = __floats2half2_rn(v.z, v.w);
        }
        __syncthreads();

        const int h  = tid & 31;
        const int ng = tid >> 5;    // node group 0..7 (8 nodes each)
        const float bb = b1[h];
        float d[8] = {0.f, 0.f, 0.f, 0.f, 0.f, 0.f, 0.f, 0.f};

        #pragma unroll 5
        for (int kq = 0; kq < 25; ++kq) {
            const int kb = kq * 4;
            const float wa = wT[kb * 33 + h];
            const float wb = wT[(kb + 1) * 33 + h];
            const float wc = wT[(kb + 2) * 33 + h];
            const float wd = wT[(kb + 3) * 33 + h];
            #pragma unroll
            for (int j = 0; j < 8; ++j) {
                uint2 uu = *(const uint2*)&xsH[(ng * 8 + j) * 50 + 2 * kq];
                float2 fa = h2f(uu.x), fb = h2f(uu.y);
                d[j] = fmaf(fa.x, wa, d[j]);
                d[j] = fmaf(fa.y, wb, d[j]);
                d[j] = fmaf(fb.x, wc, d[j]);
                d[j] = fmaf(fb.y, wd, d[j]);
            }
        }
        #pragma unroll
        for (int j = 0; j < 8; ++j) {
            float v = fmaxf(d[j] + bb, 0.f);
            float s = v * v;
            #pragma unroll
            for (int m = 16; m >= 1; m >>= 1) s += __shfl_xor(s, m, 32);
            float inv = 1.f / fmaxf(sqrtf(s), 1e-12f);
            int node = n0 + ng * 8 + j;
            if (node < N) {
                xh[(size_t)node * HID + h] = __float2half(v);
                if (h == 0) invn[node] = inv;
            }
        }
    } else {
        // ---------------- kc_sort: chunk-local counting sort by bucket = tgt>>6 ------------
        const int c = q;
        if (c >= NC) return;
        int* hist = (int*)smem;          // NBMAX ints
        int* off  = hist + NBMAX;        // NBMAX ints
        const int start = c * CHUNK;
        const int end = min(start + CHUNK, E);
        for (int b = tid; b < NB; b += 256) hist[b] = 0;
        __syncthreads();
        for (int e = start + tid; e < end; e += 256)
            atomicAdd(&hist[ei[E + e] >> 6], 1);
        __syncthreads();
        if (tid < 64) {   // wave 0: exclusive scan, 64 buckets/round with carry
            int carry = 0;
            for (int rr = 0; rr * 64 < NB; ++rr) {
                int b = rr * 64 + tid;
                int v = (b < NB) ? hist[b] : 0;
                int x = v;
                #pragma unroll
                for (int dd = 1; dd < 64; dd <<= 1) {
                    int y = __shfl_up(x, dd, 64);
                    if (tid >= dd) x += y;
                }
                if (b < NB) off[b] = carry + x - v;
                carry += __shfl(x, 63, 64);
            }
        }
        __syncthreads();
        const size_t urow = (size_t)c * (NB + 1);
        for (int b = tid; b < NB; b += 256) {
            offU[urow + b] = (unsigned short)off[b];   // coalesced u16 writes
            hist[b] = off[b];                           // reuse as local cursor
        }
        if (tid == 0) offU[urow + NB] = (unsigned short)(end - start);
        __syncthreads();
        for (int e = start + tid; e < end; e += 256) {
            int t = ei[E + e];
            int b = t >> 6;
            int pos = atomicAdd(&hist[b], 1);
            binned[start + pos] = ei[e] | ((t & 63) << 17);  // src<2^17, local 6 bits
        }
    }
}

// ================= Fused: 1 global pass -> LDS reorder -> DUAL-NODE pipelined gather =======
__global__ __launch_bounds__(256) void k_fused(
    const int* __restrict__ binned, const unsigned short* __restrict__ offU,
    const __half* __restrict__ xh, const float* __restrict__ invn,
    const float* __restrict__ pbeta,
    const float* __restrict__ w2, const float* __restrict__ b2,
    float* __restrict__ out, int N, int NB, int NC)
{
    __shared__ unsigned short b0s[NCMAX], b1s[NCMAX];
    __shared__ int cnt[LOCB], cur[LOCB];
    __shared__ int led[CAP], led2[CAP];
    __shared__ int bcur_s;
    const int tid  = threadIdx.x;
    const int lane = tid & 63;
    const int wv   = tid >> 6;
    const int g    = lane & 7;   // feature slice: halfs g*4 .. g*4+3
    const int sub  = lane >> 3;  // edge slot 0..7 (slot-uniform across its 8 lanes)
    const int b    = blockIdx.x;
    const int R    = NB + 1;
    const float beta = *pbeta;
    const float w0a = w2[g*4], w0b = w2[g*4+1], w0c = w2[g*4+2], w0d = w2[g*4+3];
    const float w1a = w2[HID+g*4], w1b = w2[HID+g*4+1], w1c = w2[HID+g*4+2], w1d = w2[HID+g*4+3];
    const float bb0 = b2[0], bb1 = b2[1];

    for (int c = tid; c < NC; c += 256) {
        const size_t base = (size_t)c * R + b;
        b0s[c] = offU[base];
        b1s[c] = offU[base + 1];
    }
    if (tid < LOCB) cnt[tid] = 0;
    if (tid == 0) bcur_s = 0;
    __syncthreads();

    // single global pass: append words into led[] unordered + per-node counts
    {
        int total = 0;
        for (int c = tid; c < NC; c += 256) total += (int)b1s[c] - (int)b0s[c];
        int pos = total ? atomicAdd(&bcur_s, total) : 0;
        for (int c = tid; c < NC; c += 256) {
            const int gbase = c * CHUNK;
            const int j1 = b1s[c];
            for (int j = b0s[c]; j < j1; ++j) {
                const int w = binned[gbase + j];
                atomicAdd(&cnt[w >> 17], 1);
                if (pos < CAP) led[pos] = w;
                ++pos;
            }
        }
    }
    __syncthreads();
    const int sz = bcur_s;
    if (tid < 64) {   // exclusive scan of 64 counts
        int v = cnt[tid], x = v;
        #pragma unroll
        for (int dd = 1; dd < 64; dd <<= 1) {
            int y = __shfl_up(x, dd, 64);
            if (tid >= dd) x += y;
        }
        cur[tid] = x - v;
    }
    __syncthreads();
    const bool fits = (sz <= CAP);
    if (fits) {   // LDS->LDS reorder: group src ids by local node
        for (int i = tid; i < sz; i += 256) {
            const int w = led[i];
            const int pos = atomicAdd(&cur[w >> 17], 1);
            led2[pos] = w & 0x1FFFF;
        }
    }
    __syncthreads();

    if (fits) {
        // dual-node gather: wave processes pair (l0, l0+4); prefetches for both nodes
        // issue back-to-back -> ~2x outstanding random loads per wave.
        for (int l0 = wv; l0 < LOCB; l0 += 8) {
            const int l1 = l0 + 4;
            const int node0 = b * LOCB + l0;
            const int node1 = b * LOCB + l1;
            const bool v0 = node0 < N, v1 = node1 < N;
            const int nr0 = v0 ? node0 : N - 1;
            const int nr1 = v1 ? node1 : N - 1;

            const float ivt0 = invn[nr0], ivt1 = invn[nr1];
            const uint2 ut0 = *(const uint2*)(xh + (size_t)nr0 * HID + g * 4);
            const uint2 ut1 = *(const uint2*)(xh + (size_t)nr1 * HID + g * 4);
            const float4 xt0 = h4_to_f4(ut0);
            const float4 xt1 = h4_to_f4(ut1);
            float sd0 = xt0.x*xt0.x + xt0.y*xt0.y + xt0.z*xt0.z + xt0.w*xt0.w;
            float sd1 = xt1.x*xt1.x + xt1.y*xt1.y + xt1.z*xt1.z + xt1.w*xt1.w;
            sd0 += __shfl_xor(sd0, 1, 64); sd0 += __shfl_xor(sd0, 2, 64); sd0 += __shfl_xor(sd0, 4, 64);
            sd1 += __shfl_xor(sd1, 1, 64); sd1 += __shfl_xor(sd1, 2, 64); sd1 += __shfl_xor(sd1, 4, 64);

            const int deg0 = cnt[l0], deg1 = cnt[l1];
            const int st0 = cur[l0] - deg0, st1 = cur[l1] - deg1;

            float a00=0.f, a01=0.f, a02=0.f, a03=0.f, ds0=0.f;
            float a10=0.f, a11=0.f, a12=0.f, a13=0.f, ds1=0.f;

            bool ok0 = sub < deg0, ok1 = sub < deg1;
            int sc0 = led2[ok0 ? st0 + sub : 0]; sc0 = ok0 ? sc0 : 0;
            int sc1 = led2[ok1 ? st1 + sub : 0]; sc1 = ok1 ? sc1 : 0;
            uint2 uc0 = *(const uint2*)(xh + (size_t)sc0 * HID + g * 4);
            uint2 uc1 = *(const uint2*)(xh + (size_t)sc1 * HID + g * 4);
            float ivc0 = invn[sc0], ivc1 = invn[sc1];

            const int dmax = deg0 > deg1 ? deg0 : deg1;
            for (int e0 = 0; e0 < dmax; e0 += 8) {
                const int en = e0 + 8 + sub;
                const bool okn0 = en < deg0, okn1 = en < deg1;
                int sn0 = led2[okn0 ? st0 + en : 0]; sn0 = okn0 ? sn0 : 0;
                int sn1 = led2[okn1 ? st1 + en : 0]; sn1 = okn1 ? sn1 : 0;
                const uint2 un0 = *(const uint2*)(xh + (size_t)sn0 * HID + g * 4);
                const uint2 un1 = *(const uint2*)(xh + (size_t)sn1 * HID + g * 4);
                const float ivn0 = invn[sn0], ivn1 = invn[sn1];

                {
                    const float4 xs = h4_to_f4(uc0);
                    float p = xt0.x*xs.x + xt0.y*xs.y + xt0.z*xs.z + xt0.w*xs.w;
                    p += __shfl_xor(p, 1, 64); p += __shfl_xor(p, 2, 64); p += __shfl_xor(p, 4, 64);
                    const float wgt = ok0 ? __expf(beta * p * ivt0 * ivc0) : 0.f;
                    a00 += wgt*xs.x; a01 += wgt*xs.y; a02 += wgt*xs.z; a03 += wgt*xs.w;
                    ds0 += wgt;
                }
                {
                    const float4 xs = h4_to_f4(uc1);
                    float p = xt1.x*xs.x + xt1.y*xs.y + xt1.z*xs.z + xt1.w*xs.w;
                    p += __shfl_xor(p, 1, 64); p += __shfl_xor(p, 2, 64); p += __shfl_xor(p, 4, 64);
                    const float wgt = ok1 ? __expf(beta * p * ivt1 * ivc1) : 0.f;
                    a10 += wgt*xs.x; a11 += wgt*xs.y; a12 += wgt*xs.z; a13 += wgt*xs.w;
                    ds1 += wgt;
                }
                uc0 = un0; ivc0 = ivn0; ok0 = okn0;
                uc1 = un1; ivc1 = ivn1; ok1 = okn1;
            }
            #pragma unroll
            for (int m = 8; m <= 32; m <<= 1) {
                a00 += __shfl_xor(a00, m, 64); a01 += __shfl_xor(a01, m, 64);
                a02 += __shfl_xor(a02, m, 64); a03 += __shfl_xor(a03, m, 64);
                ds0 += __shfl_xor(ds0, m, 64);
                a10 += __shfl_xor(a10, m, 64); a11 += __shfl_xor(a11, m, 64);
                a12 += __shfl_xor(a12, m, 64); a13 += __shfl_xor(a13, m, 64);
                ds1 += __shfl_xor(ds1, m, 64);
            }
            // self-loops + epilogue
            const float ws0 = __expf(beta * sd0 * ivt0 * ivt0);
            const float ws1 = __expf(beta * sd1 * ivt1 * ivt1);
            a00 += ws0*xt0.x; a01 += ws0*xt0.y; a02 += ws0*xt0.z; a03 += ws0*xt0.w; ds0 += ws0;
            a10 += ws1*xt1.x; a11 += ws1*xt1.y; a12 += ws1*xt1.z; a13 += ws1*xt1.w; ds1 += ws1;

            {
                const float invd = 1.f / ds0;
                const float o0 = a00*invd, o1 = a01*invd, o2 = a02*invd, o3 = a03*invd;
                float l0v = o0*w0a + o1*w0b + o2*w0c + o3*w0d;
                float l1v = o0*w1a + o1*w1b + o2*w1c + o3*w1d;
                l0v += __shfl_xor(l0v, 1, 64); l0v += __shfl_xor(l0v, 2, 64); l0v += __shfl_xor(l0v, 4, 64);
                l1v += __shfl_xor(l1v, 1, 64); l1v += __shfl_xor(l1v, 2, 64); l1v += __shfl_xor(l1v, 4, 64);
                if (lane == 0 && v0) {
                    l0v += bb0; l1v += bb1;
                    float m = fmaxf(l0v, l1v);
                    float lse = m + __logf(__expf(l0v - m) + __expf(l1v - m));
                    out[2 * (size_t)node0]     = l0v - lse;
                    out[2 * (size_t)node0 + 1] = l1v - lse;
                }
            }
            {
                const float invd = 1.f / ds1;
                const float o0 = a10*invd, o1 = a11*invd, o2 = a12*invd, o3 = a13*invd;
                float l0v = o0*w0a + o1*w0b + o2*w0c + o3*w0d;
                float l1v = o0*w1a + o1*w1b + o2*w1c + o3*w1d;
                l0v += __shfl_xor(l0v, 1, 64); l0v += __shfl_xor(l0v, 2, 64); l0v += __shfl_xor(l0v, 4, 64);
                l1v += __shfl_xor(l1v, 1, 64); l1v += __shfl_xor(l1v, 2, 64); l1v += __shfl_xor(l1v, 4, 64);
                if (lane == 0 && v1) {
                    l0v += bb0; l1v += bb1;
                    float m = fmaxf(l0v, l1v);
                    float lse = m + __logf(__expf(l0v - m) + __expf(l1v - m));
                    out[2 * (size_t)node1]     = l0v - lse;
                    out[2 * (size_t)node1 + 1] = l1v - lse;
                }
            }
        }
    } else {
        // fallback (bucket > CAP, practically never): filter all sub-runs from global
        for (int local = wv; local < LOCB; local += 4) {
            const int node = b * LOCB + local;
            if (node >= N) break;
            const float ivt = invn[node];
            const uint2 ut = *(const uint2*)(xh + (size_t)node * HID + g * 4);
            const float4 xt = h4_to_f4(ut);
            float sd = xt.x*xt.x + xt.y*xt.y + xt.z*xt.z + xt.w*xt.w;
            sd += __shfl_xor(sd, 1, 64); sd += __shfl_xor(sd, 2, 64); sd += __shfl_xor(sd, 4, 64);
            float a0 = 0.f, a1 = 0.f, a2 = 0.f, a3 = 0.f, dsum = 0.f;
            for (int c = 0; c < NC; ++c) {
                const int gbase = c * CHUNK;
                const int j1 = b1s[c];
                for (int j = (int)b0s[c] + sub; j < j1; j += 8) {
                    const int wrd = binned[gbase + j];
                    const bool ok2 = ((wrd >> 17) == local);
                    const int s_ = ok2 ? (wrd & 0x1FFFF) : 0;
                    const uint2 us = *(const uint2*)(xh + (size_t)s_ * HID + g * 4);
                    const float4 xs = h4_to_f4(us);
                    float p = xt.x*xs.x + xt.y*xs.y + xt.z*xs.z + xt.w*xs.w;
                    p += __shfl_xor(p, 1, 64); p += __shfl_xor(p, 2, 64); p += __shfl_xor(p, 4, 64);
                    const float ivs = invn[s_];
                    const float wgt = ok2 ? __expf(beta * p * ivt * ivs) : 0.f;
                    a0 += wgt*xs.x; a1 += wgt*xs.y; a2 += wgt*xs.z; a3 += wgt*xs.w;
                    dsum += wgt;
                }
            }
            #pragma unroll
            for (int m = 8; m <= 32; m <<= 1) {
                a0 += __shfl_xor(a0, m, 64); a1 += __shfl_xor(a1, m, 64);
                a2 += __shfl_xor(a2, m, 64); a3 += __shfl_xor(a3, m, 64);
                dsum += __shfl_xor(dsum, m, 64);
            }
            const float wself = __expf(beta * sd * ivt * ivt);
            a0 += wself*xt.x; a1 += wself*xt.y; a2 += wself*xt.z; a3 += wself*xt.w;
            dsum += wself;
            const float invd = 1.f / dsum;
            const float o0 = a0*invd, o1 = a1*invd, o2 = a2*invd, o3 = a3*invd;
            float l0 = o0*w0a + o1*w0b + o2*w0c + o3*w0d;
            float l1 = o0*w1a + o1*w1b + o2*w1c + o3*w1d;
            l0 += __shfl_xor(l0, 1, 64); l0 += __shfl_xor(l0, 2, 64); l0 += __shfl_xor(l0, 4, 64);
            l1 += __shfl_xor(l1, 1, 64); l1 += __shfl_xor(l1, 2, 64); l1 += __shfl_xor(l1, 4, 64);
            if (lane == 0) {
                l0 += bb0; l1 += bb1;
                float m = fmaxf(l0, l1);
                float lse = m + __logf(__expf(l0 - m) + __expf(l1 - m));
                out[2 * (size_t)node]     = l0 - lse;
                out[2 * (size_t)node + 1] = l1 - lse;
            }
        }
    }
}

extern "C" void kernel_launch(void* const* d_in, const int* in_sizes, int n_in,
                              void* d_out, int out_size, void* d_ws, size_t ws_size,
                              hipStream_t stream) {
    const float* X    = (const float*)d_in[0];
    const float* w1   = (const float*)d_in[1];
    const float* b1   = (const float*)d_in[2];
    const float* beta = (const float*)d_in[3];
    const float* w2   = (const float*)d_in[4];
    const float* b2   = (const float*)d_in[5];
    const int*   ei   = (const int*)d_in[6];

    const int N = in_sizes[0] / NFEAT;        // 100000
    const int E = in_sizes[6] / 2;            // 1600000
    const int NB = (N + LOCB - 1) / LOCB;     // 1563 buckets of 64 nodes
    const int NC = (E + CHUNK - 1) / CHUNK;   // 391 chunks
    const int R  = NB + 1;                    // offset-table row length
    const int nblk1 = (N + 63) / 64;          // 1563 k1 units

    char* wsb = (char*)d_ws;
    __half* xhp   = (__half*)wsb;                 wsb += (size_t)N * HID * 2;   // 6.4 MB
    float*  invn  = (float*)wsb;                  wsb += (size_t)N * 4;
    int*    binned = (int*)wsb;                   wsb += (size_t)E * 4;         // 6.4 MB
    unsigned short* offU = (unsigned short*)wsb;  wsb += (size_t)NC * R * 2;    // 1.2 MB
    float* out = (float*)d_out;

    const int k1grp = (nblk1 + 3) / 4;            // 391
    const int gridA = (k1grp > NC ? k1grp : NC) * 5;   // 1955 interleaved blocks

    k_phase1<<<gridA, 256, 0, stream>>>(X, w1, b1, ei, xhp, invn,
                                        binned, offU, N, E, NB, NC, nblk1);
    k_fused<<<NB, 256, 0, stream>>>(binned, offU, xhp, invn, beta, w2, b2, out, N, NB, NC);
}